// Round 1
// baseline (3444.732 us; speedup 1.0000x reference)
//
#include <hip/hip_runtime.h>

__device__ __forceinline__ float4 ld4(const float* p){ return *reinterpret_cast<const float4*>(p); }
__device__ __forceinline__ void st4(float* p, const float4& v){ *reinterpret_cast<float4*>(p) = v; }

// ===================== generic fp32 tiled GEMM =====================
// C[r][c] = sum_k A[r][k]*B(k,c) (+bias(+bias2)) ; optional accumulate into C, relu.
// BT=0: B is [K][M] row-major (ldb=M). BT=1: B is [M][K] row-major (ldb=K) -> C = A*B^T.
// Requires K%16==0, M multiple of 64 (grid.y covers M/64). Row tail guarded by nrows.
template<int BT>
__global__ __launch_bounds__(256)
void gemm_kernel(const float* __restrict__ A, int lda,
                 const float* __restrict__ B, int ldb,
                 float* __restrict__ C, int ldc,
                 const float* __restrict__ bias, const float* __restrict__ bias2,
                 int nrows, int K, int relu, int accum)
{
  __shared__ float As[16][68];
  __shared__ float Bs[16][68];
  const int tid = threadIdx.x;
  const int tx = tid & 15, ty = tid >> 4;
  const int rowbase = blockIdx.x * 64;
  const int colbase = blockIdx.y * 64;
  const int lrow = tid >> 2;          // 0..63
  const int lkq  = (tid & 3) << 2;    // 0,4,8,12

  float acc[4][4];
#pragma unroll
  for (int i = 0; i < 4; ++i)
#pragma unroll
    for (int j = 0; j < 4; ++j) acc[i][j] = 0.f;

  for (int k0 = 0; k0 < K; k0 += 16) {
    int ar = rowbase + lrow;
    float4 av = make_float4(0.f, 0.f, 0.f, 0.f);
    if (ar < nrows) av = ld4(A + (size_t)ar * lda + k0 + lkq);
    float4 bv;
    if (BT) {
      bv = ld4(B + (size_t)(colbase + lrow) * ldb + k0 + lkq);
    } else {
      bv = ld4(B + (size_t)(k0 + (tid >> 4)) * ldb + colbase + ((tid & 15) << 2));
    }
    __syncthreads();
    As[lkq + 0][lrow] = av.x; As[lkq + 1][lrow] = av.y;
    As[lkq + 2][lrow] = av.z; As[lkq + 3][lrow] = av.w;
    if (BT) {
      Bs[lkq + 0][lrow] = bv.x; Bs[lkq + 1][lrow] = bv.y;
      Bs[lkq + 2][lrow] = bv.z; Bs[lkq + 3][lrow] = bv.w;
    } else {
      st4(&Bs[tid >> 4][(tid & 15) << 2], bv);
    }
    __syncthreads();
#pragma unroll
    for (int kk = 0; kk < 16; ++kk) {
      float4 a = ld4(&As[kk][ty << 2]);
      float4 b = ld4(&Bs[kk][tx << 2]);
      acc[0][0] = fmaf(a.x, b.x, acc[0][0]); acc[0][1] = fmaf(a.x, b.y, acc[0][1]);
      acc[0][2] = fmaf(a.x, b.z, acc[0][2]); acc[0][3] = fmaf(a.x, b.w, acc[0][3]);
      acc[1][0] = fmaf(a.y, b.x, acc[1][0]); acc[1][1] = fmaf(a.y, b.y, acc[1][1]);
      acc[1][2] = fmaf(a.y, b.z, acc[1][2]); acc[1][3] = fmaf(a.y, b.w, acc[1][3]);
      acc[2][0] = fmaf(a.z, b.x, acc[2][0]); acc[2][1] = fmaf(a.z, b.y, acc[2][1]);
      acc[2][2] = fmaf(a.z, b.z, acc[2][2]); acc[2][3] = fmaf(a.z, b.w, acc[2][3]);
      acc[3][0] = fmaf(a.w, b.x, acc[3][0]); acc[3][1] = fmaf(a.w, b.y, acc[3][1]);
      acc[3][2] = fmaf(a.w, b.z, acc[3][2]); acc[3][3] = fmaf(a.w, b.w, acc[3][3]);
    }
  }

  const int col0 = colbase + (tx << 2);
  float4 bv4 = make_float4(0.f, 0.f, 0.f, 0.f);
  if (bias)  { float4 t = ld4(bias  + col0); bv4.x += t.x; bv4.y += t.y; bv4.z += t.z; bv4.w += t.w; }
  if (bias2) { float4 t = ld4(bias2 + col0); bv4.x += t.x; bv4.y += t.y; bv4.z += t.z; bv4.w += t.w; }
#pragma unroll
  for (int i = 0; i < 4; ++i) {
    int r = rowbase + (ty << 2) + i;
    if (r >= nrows) continue;
    float* cp = C + (size_t)r * ldc + col0;
    float4 v = make_float4(acc[i][0] + bv4.x, acc[i][1] + bv4.y,
                           acc[i][2] + bv4.z, acc[i][3] + bv4.w);
    if (accum) { float4 o = ld4(cp); v.x += o.x; v.y += o.y; v.z += o.z; v.w += o.w; }
    if (relu) { v.x = fmaxf(v.x, 0.f); v.y = fmaxf(v.y, 0.f); v.z = fmaxf(v.z, 0.f); v.w = fmaxf(v.w, 0.f); }
    st4(cp, v);
  }
}

// ===================== encoder tail: itype part + bias + relu + mask =====================
__global__ void encoder_finish_kernel(float* __restrict__ h0, const float* __restrict__ itype,
                                      const float* __restrict__ mask, const float* __restrict__ Wenc,
                                      const float* __restrict__ benc, int n)
{
  int idx = blockIdx.x * blockDim.x + threadIdx.x;
  if (idx >= n * 128) return;
  int nn = idx >> 7, j = idx & 127;
  float v = h0[idx]
          + itype[nn * 3 + 0] * Wenc[128 * 128 + j]
          + itype[nn * 3 + 1] * Wenc[129 * 128 + j]
          + itype[nn * 3 + 2] * Wenc[130 * 128 + j]
          + benc[j];
  h0[idx] = fmaxf(v, 0.f) * mask[nn];
}

// ===================== CSR build =====================
__global__ void count_kernel(const int* __restrict__ dst, int* __restrict__ cnt, int E, int EP)
{
  int e = blockIdx.x * blockDim.x + threadIdx.x;
  if (e >= EP) return;
  int d = (e < E) ? dst[e] : (e - E);
  atomicAdd(&cnt[d], 1);
}

__global__ void scan_kernel(const int* __restrict__ cnt, int* __restrict__ indptr, int n)
{
  __shared__ int wsum[16];
  int tid = threadIdx.x;
  int lane = tid & 63, wv = tid >> 6;
  int run = 0;
  for (int base = 0; base < n; base += 1024) {
    int idx = base + tid;
    int v = (idx < n) ? cnt[idx] : 0;
    int x = v;
#pragma unroll
    for (int off = 1; off < 64; off <<= 1) { int y = __shfl_up(x, off); if (lane >= off) x += y; }
    if (lane == 63) wsum[wv] = x;
    __syncthreads();
    if (wv == 0) {
      int t = (lane < 16) ? wsum[lane] : 0;
#pragma unroll
      for (int off = 1; off < 16; off <<= 1) { int y = __shfl_up(t, off); if (lane >= off) t += y; }
      if (lane < 16) wsum[lane] = t;
    }
    __syncthreads();
    int offs = wv ? wsum[wv - 1] : 0;
    int tot = wsum[15];
    if (idx < n) indptr[idx] = run + offs + x - v;   // exclusive prefix
    run += tot;
    __syncthreads();
  }
  if (tid == 0) indptr[n] = run;
}

__global__ void fill_kernel(const int* __restrict__ src, const int* __restrict__ dst,
                            const int* __restrict__ indptr, int* __restrict__ fillc,
                            int* __restrict__ srcl, int E, int EP)
{
  int e = blockIdx.x * blockDim.x + threadIdx.x;
  if (e >= EP) return;
  int d, s;
  if (e < E) { d = dst[e]; s = src[e]; } else { d = e - E; s = e - E; }
  int pos = atomicAdd(&fillc[d], 1);
  srcl[indptr[d] + pos] = s;
}

// ===================== GAT: per-node attention logits =====================
__global__ void gat_att_kernel(const float* __restrict__ xh, const float* __restrict__ attS,
                               const float* __restrict__ attD, float* __restrict__ aS,
                               float* __restrict__ aD, int n)
{
  int idx = blockIdx.x * blockDim.x + threadIdx.x;
  if (idx >= n * 4) return;
  int nn = idx >> 2, hd = idx & 3;
  const float* xr = xh + (size_t)nn * 128 + hd * 32;
  const float* as_ = attS + hd * 32;
  const float* ad_ = attD + hd * 32;
  float s = 0.f, d = 0.f;
#pragma unroll
  for (int o = 0; o < 32; ++o) { float v = xr[o]; s = fmaf(v, as_[o], s); d = fmaf(v, ad_[o], d); }
  aS[idx] = s; aD[idx] = d;
}

// ===================== GAT: edge-softmax aggregation (one wave per dst) =====================
__global__ __launch_bounds__(256)
void gat_agg_kernel(const float* __restrict__ xh, const float* __restrict__ aS,
                    const float* __restrict__ aD, const int* __restrict__ indptr,
                    const int* __restrict__ srcl, const float* __restrict__ bgat,
                    float* __restrict__ out, int ldo, int n)
{
  int wid = (int)((blockIdx.x * (size_t)blockDim.x + threadIdx.x) >> 6);
  int lane = threadIdx.x & 63;
  if (wid >= n) return;
  int eb = indptr[wid], ee = indptr[wid + 1];
  float d0 = aD[wid * 4 + 0], d1 = aD[wid * 4 + 1], d2 = aD[wid * 4 + 2], d3 = aD[wid * 4 + 3];
  // pass A: per-head max (lane-parallel over edges)
  float m0 = -3e38f, m1 = -3e38f, m2 = -3e38f, m3 = -3e38f;
  for (int i = eb + lane; i < ee; i += 64) {
    int s = srcl[i];
    float e0 = aS[s * 4 + 0] + d0; e0 = e0 > 0.f ? e0 : 0.2f * e0; m0 = fmaxf(m0, e0);
    float e1 = aS[s * 4 + 1] + d1; e1 = e1 > 0.f ? e1 : 0.2f * e1; m1 = fmaxf(m1, e1);
    float e2 = aS[s * 4 + 2] + d2; e2 = e2 > 0.f ? e2 : 0.2f * e2; m2 = fmaxf(m2, e2);
    float e3 = aS[s * 4 + 3] + d3; e3 = e3 > 0.f ? e3 : 0.2f * e3; m3 = fmaxf(m3, e3);
  }
#pragma unroll
  for (int off = 32; off; off >>= 1) {
    m0 = fmaxf(m0, __shfl_xor(m0, off));
    m1 = fmaxf(m1, __shfl_xor(m1, off));
    m2 = fmaxf(m2, __shfl_xor(m2, off));
    m3 = fmaxf(m3, __shfl_xor(m3, off));
  }
  // pass B: unnormalized weighted sum + denominators (whole wave per edge)
  float s0 = 0.f, s1 = 0.f, s2 = 0.f, s3 = 0.f, acc0 = 0.f, acc1 = 0.f;
  bool hi = lane >= 32;
  for (int i = eb; i < ee; ++i) {
    int s = srcl[i];
    float e0 = aS[s * 4 + 0] + d0; e0 = e0 > 0.f ? e0 : 0.2f * e0; float p0 = __expf(e0 - m0);
    float e1 = aS[s * 4 + 1] + d1; e1 = e1 > 0.f ? e1 : 0.2f * e1; float p1 = __expf(e1 - m1);
    float e2 = aS[s * 4 + 2] + d2; e2 = e2 > 0.f ? e2 : 0.2f * e2; float p2 = __expf(e2 - m2);
    float e3 = aS[s * 4 + 3] + d3; e3 = e3 > 0.f ? e3 : 0.2f * e3; float p3 = __expf(e3 - m3);
    s0 += p0; s1 += p1; s2 += p2; s3 += p3;
    float plo = hi ? p1 : p0;
    float phi = hi ? p3 : p2;
    acc0 = fmaf(plo, xh[(size_t)s * 128 + lane], acc0);
    acc1 = fmaf(phi, xh[(size_t)s * 128 + 64 + lane], acc1);
  }
  float dlo = (hi ? s1 : s0) + 1e-16f;
  float dhi = (hi ? s3 : s2) + 1e-16f;
  out[(size_t)wid * ldo + lane]      = acc0 / dlo + bgat[lane];
  out[(size_t)wid * ldo + 64 + lane] = acc1 / dhi + bgat[64 + lane];
}

// ===================== impact head second layer + |.| mean accumulation =====================
__global__ __launch_bounds__(256)
void impact_out_kernel(const float* __restrict__ hid, const float* __restrict__ W2,
                       const float* __restrict__ b2, float* __restrict__ outp,
                       float* __restrict__ total, float wk, int n)
{
  __shared__ float red[256];
  int idx = blockIdx.x * 256 + threadIdx.x;
  float part = 0.f;
  if (idx < n) {
    const float* h = hid + (size_t)idx * 64;
    float o0 = b2[0], o1 = b2[1], o2 = b2[2];
#pragma unroll 8
    for (int k = 0; k < 64; ++k) {
      float v = h[k];
      o0 = fmaf(v, W2[k * 3 + 0], o0);
      o1 = fmaf(v, W2[k * 3 + 1], o1);
      o2 = fmaf(v, W2[k * 3 + 2], o2);
    }
    outp[(size_t)idx * 3 + 0] = o0;
    outp[(size_t)idx * 3 + 1] = o1;
    outp[(size_t)idx * 3 + 2] = o2;
    part = fabsf(o0) + fabsf(o1) + fabsf(o2);
  }
  red[threadIdx.x] = part;
  __syncthreads();
  for (int s = 128; s; s >>= 1) {
    if (threadIdx.x < s) red[threadIdx.x] += red[threadIdx.x + s];
    __syncthreads();
  }
  if (threadIdx.x == 0) atomicAdd(total, red[0] * wk);
}

// ===================== LSTM pointwise =====================
__global__ void lstm_pw_kernel(const float* __restrict__ gates, float* __restrict__ c,
                               float* __restrict__ hout, int ldh,
                               float* __restrict__ hlast, int n)
{
  int idx = blockIdx.x * blockDim.x + threadIdx.x;
  if (idx >= n * 128) return;
  int nn = idx >> 7, j = idx & 127;
  const float* g = gates + (size_t)nn * 512;
  float gi = g[j], gf = g[128 + j], gg = g[256 + j], go = g[384 + j];
  float si = 1.f / (1.f + __expf(-gi));
  float sf = 1.f / (1.f + __expf(-gf));
  float so = 1.f / (1.f + __expf(-go));
  float cc = sf * c[idx] + si * tanhf(gg);
  float hh = so * tanhf(cc);
  c[idx] = cc;
  hout[(size_t)nn * ldh + j] = hh;
  if (hlast) hlast[idx] = hh;
}

// ===================== host =====================
extern "C" void kernel_launch(void* const* d_in, const int* in_sizes, int n_in,
                              void* d_out, int out_size, void* d_ws, size_t ws_size,
                              hipStream_t stream)
{
  const float* x     = (const float*)d_in[0];
  const int*   ei    = (const int*)  d_in[1];
  const float* mask  = (const float*)d_in[2];
  const float* itype = (const float*)d_in[3];
  const float* Wenc  = (const float*)d_in[4];
  const float* benc  = (const float*)d_in[5];
  const float* Wgat  = (const float*)d_in[6];
  const float* attS  = (const float*)d_in[7];
  const float* attD  = (const float*)d_in[8];
  const float* bgat  = (const float*)d_in[9];
  const float* W1    = (const float*)d_in[10];
  const float* b1    = (const float*)d_in[11];
  const float* W2    = (const float*)d_in[12];
  const float* b2    = (const float*)d_in[13];
  const float* Wih0  = (const float*)d_in[14];
  const float* Whh0  = (const float*)d_in[15];
  const float* bih0  = (const float*)d_in[16];
  const float* bhh0  = (const float*)d_in[17];
  const float* Wih1  = (const float*)d_in[18];
  const float* Whh1  = (const float*)d_in[19];
  const float* bih1  = (const float*)d_in[20];
  const float* bhh1  = (const float*)d_in[21];

  const int N  = in_sizes[0] / 128;
  const int E  = in_sizes[1] / 2;
  const int EP = E + N;

  float* out      = (float*)d_out;
  float* impacts  = out;                                   // 3 blocks of N*3
  float* temporal = out + (size_t)3 * N * 3;               // [N][3][128] (also hop storage)
  float* hlast    = temporal + (size_t)N * 3 * 128;        // [N][128]
  float* total    = hlast + (size_t)N * 128;               // scalar

  float* ws = (float*)d_ws;
  float* h0 = ws;                         // N*128 (aliased by LSTM gates later)
  float* xh = h0 + (size_t)N * 128;       // N*128 (also imp hidden [N,64]; aliased by gates)
  float* gates = h0;                      // NC*512 where NC = N/2  (== 2*N*128 floats)
  float* aS = xh + (size_t)N * 128;       // N*4
  float* aD = aS + (size_t)N * 4;         // N*4
  float* hA = aD + (size_t)N * 4;         // N*128
  float* cA = hA + (size_t)N * 128;       // N*128
  float* cB = cA + (size_t)N * 128;       // N*128
  int* indptr = (int*)(cB + (size_t)N * 128);  // N+1
  int* fillc  = indptr + (N + 1);              // N
  int* srcl   = fillc + N;                     // EP

  size_t need = ((size_t)5 * N * 128 + 8 * N) * 4 + ((size_t)2 * N + 1 + EP) * 4;
  if (ws_size < need) return;  // cannot proceed safely

  const int* esrc = ei;
  const int* edst = ei + E;

  // ---- CSR by destination (with self-loops appended) ----
  hipMemsetAsync(fillc, 0, (size_t)N * sizeof(int), stream);
  count_kernel<<<(EP + 255) / 256, 256, 0, stream>>>(edst, fillc, E, EP);
  scan_kernel<<<1, 1024, 0, stream>>>(fillc, indptr, N);
  hipMemsetAsync(fillc, 0, (size_t)N * sizeof(int), stream);
  fill_kernel<<<(EP + 255) / 256, 256, 0, stream>>>(esrc, edst, indptr, fillc, srcl, E, EP);

  const int rowTiles = (N + 63) / 64;

  // ---- encoder: h0 = relu([x|itype] @ Wenc + b) * mask ----
  gemm_kernel<0><<<dim3(rowTiles, 2), 256, 0, stream>>>(x, 128, Wenc, 128, h0, 128,
                                                        nullptr, nullptr, N, 128, 0, 0);
  encoder_finish_kernel<<<(N * 128 + 255) / 256, 256, 0, stream>>>(h0, itype, mask, Wenc, benc, N);

  hipMemsetAsync(total, 0, sizeof(float), stream);

  // ---- 3 GAT hops + impact heads ----
  for (int k = 0; k < 3; ++k) {
    const float* hin = (k == 0) ? h0 : (temporal + (size_t)(k - 1) * 128);
    int ldin = (k == 0) ? 128 : 384;
    gemm_kernel<0><<<dim3(rowTiles, 2), 256, 0, stream>>>(hin, ldin, Wgat + (size_t)k * 128 * 128, 128,
                                                          xh, 128, nullptr, nullptr, N, 128, 0, 0);
    gat_att_kernel<<<(N * 4 + 255) / 256, 256, 0, stream>>>(xh, attS + k * 128, attD + k * 128, aS, aD, N);
    gat_agg_kernel<<<(N * 64 + 255) / 256, 256, 0, stream>>>(xh, aS, aD, indptr, srcl, bgat + k * 128,
                                                             temporal + (size_t)k * 128, 384, N);
    gemm_kernel<0><<<dim3(rowTiles, 1), 256, 0, stream>>>(temporal + (size_t)k * 128, 384,
                                                          W1 + (size_t)k * 128 * 64, 64,
                                                          xh, 64, b1 + k * 64, nullptr, N, 128, 1, 0);
    float wk = ((k == 0) ? 1.f : (k == 1) ? 0.5f : 0.25f) / (3.0f * (float)N);
    impact_out_kernel<<<(N + 255) / 256, 256, 0, stream>>>(xh, W2 + k * 64 * 3, b2 + k * 3,
                                                           impacts + (size_t)k * N * 3, total, wk, N);
  }

  // ---- 2-layer LSTM over T=3 (node-chunked so gates fit in h0+xh alias) ----
  hipMemsetAsync(cA, 0, (size_t)N * 128 * sizeof(float), stream);
  hipMemsetAsync(cB, 0, (size_t)N * 128 * sizeof(float), stream);
  const int NC = N / 2;
  for (int t = 0; t < 3; ++t) {
    for (int c0 = 0; c0 < N; c0 += NC) {
      int nr = (N - c0 < NC) ? (N - c0) : NC;
      int rt = (nr + 63) / 64;
      // layer 0
      gemm_kernel<1><<<dim3(rt, 8), 256, 0, stream>>>(temporal + (size_t)c0 * 384 + (size_t)t * 128, 384,
                                                      Wih0, 128, gates, 512,
                                                      bih0, (t == 0 ? bhh0 : nullptr), nr, 128, 0, 0);
      if (t > 0)
        gemm_kernel<1><<<dim3(rt, 8), 256, 0, stream>>>(hA + (size_t)c0 * 128, 128, Whh0, 128,
                                                        gates, 512, bhh0, nullptr, nr, 128, 0, 1);
      lstm_pw_kernel<<<(nr * 128 + 255) / 256, 256, 0, stream>>>(gates, cA + (size_t)c0 * 128,
                                                                 hA + (size_t)c0 * 128, 128, nullptr, nr);
      // layer 1
      gemm_kernel<1><<<dim3(rt, 8), 256, 0, stream>>>(hA + (size_t)c0 * 128, 128, Wih1, 128,
                                                      gates, 512, bih1, (t == 0 ? bhh1 : nullptr),
                                                      nr, 128, 0, 0);
      if (t > 0)
        gemm_kernel<1><<<dim3(rt, 8), 256, 0, stream>>>(temporal + (size_t)c0 * 384 + (size_t)(t - 1) * 128, 384,
                                                        Whh1, 128, gates, 512, bhh1, nullptr, nr, 128, 0, 1);
      lstm_pw_kernel<<<(nr * 128 + 255) / 256, 256, 0, stream>>>(gates, cB + (size_t)c0 * 128,
                                                                 temporal + (size_t)c0 * 384 + (size_t)t * 128, 384,
                                                                 (t == 2 ? hlast + (size_t)c0 * 128 : nullptr), nr);
    }
  }
}

// Round 2
// 2205.878 us; speedup vs baseline: 1.5616x; 1.5616x over previous
//
#include <hip/hip_runtime.h>

typedef __attribute__((ext_vector_type(8))) short short8;
typedef __attribute__((ext_vector_type(4))) float f32x4;

__device__ __forceinline__ float4 ld4(const float* p){ return *reinterpret_cast<const float4*>(p); }
__device__ __forceinline__ void st4(float* p, const float4& v){ *reinterpret_cast<float4*>(p) = v; }

__device__ __forceinline__ unsigned short f2b(float x){
  unsigned int u = __float_as_uint(x);
  unsigned int r = (u + 0x7fffu + ((u >> 16) & 1u)) >> 16;
  return (unsigned short)r;
}
__device__ __forceinline__ float b2f(unsigned short b){
  return __uint_as_float(((unsigned int)b) << 16);
}

__device__ __forceinline__ short8 cvt_frag(float4 f0, float4 f1){
  short8 a;
  a[0]=(short)f2b(f0.x); a[1]=(short)f2b(f0.y); a[2]=(short)f2b(f0.z); a[3]=(short)f2b(f0.w);
  a[4]=(short)f2b(f1.x); a[5]=(short)f2b(f1.y); a[6]=(short)f2b(f1.z); a[7]=(short)f2b(f1.w);
  return a;
}

// ============ weight fragmentization ============
// k-major source: B[k][col] (ldb = cols). Layout: BF[((kb*CTG+ctg)*64+lane)*8+j]
__global__ void build_frag_kmajor(const float* __restrict__ B, int ldb,
                                  unsigned short* __restrict__ BF, int KB, int CTG)
{
  int idx = blockIdx.x * 256 + threadIdx.x;
  int total = KB * CTG * 512;
  if (idx >= total) return;
  int j = idx & 7, lane = (idx >> 3) & 63, rest = idx >> 9;
  int ctg = rest % CTG, kb = rest / CTG;
  int k = kb * 32 + ((lane >> 4) << 3) + j;
  int col = ctg * 16 + (lane & 15);
  BF[idx] = f2b(B[(size_t)k * ldb + col]);
}

// LSTM combined: B^T[k][col] = W[col][k]; k<128 -> Wih, else Whh. KB=8, CTG=32.
__global__ void build_frag_lstm(const float* __restrict__ Wih, const float* __restrict__ Whh,
                                unsigned short* __restrict__ BF)
{
  int idx = blockIdx.x * 256 + threadIdx.x;
  if (idx >= 131072) return;
  int j = idx & 7, lane = (idx >> 3) & 63, rest = idx >> 9;
  int ctg = rest & 31, kb = rest >> 5;
  int k = kb * 32 + ((lane >> 4) << 3) + j;
  int col = ctg * 16 + (lane & 15);
  float v = (k < 128) ? Wih[(size_t)col * 128 + k] : Whh[(size_t)col * 128 + (k - 128)];
  BF[idx] = f2b(v);
}

// ============ generic MFMA GEMM: C[N x (CTG*16)] = A[N x KB*32] * B ============
template<int CT, int KB, int OUTBF, int RELU>
__global__ __launch_bounds__(256)
void gemm_mfma(const float* __restrict__ A, int lda,
               const unsigned short* __restrict__ BF, int ctgTot,
               float* __restrict__ Cf, unsigned short* __restrict__ Cb, int ldc,
               const float* __restrict__ bias, int nrows)
{
  const int tid = threadIdx.x, lane = tid & 63, wid = tid >> 6;
  const int row0 = blockIdx.x * 64 + wid * 16;
  const int cg = blockIdx.y * CT;
  const int r = row0 + (lane & 15);
  const bool rok = r < nrows;
  const int koff = (lane >> 4) << 3;

  f32x4 acc[CT];
#pragma unroll
  for (int ct = 0; ct < CT; ++ct) {
    float b = bias ? bias[(cg + ct) * 16 + (lane & 15)] : 0.f;
    acc[ct] = (f32x4){b, b, b, b};
  }

  for (int kb = 0; kb < KB; ++kb) {
    short8 a = {};
    if (rok) {
      const float* p = A + (size_t)r * lda + kb * 32 + koff;
      a = cvt_frag(ld4(p), ld4(p + 4));
    }
#pragma unroll
    for (int ct = 0; ct < CT; ++ct) {
      const short8 b = *(const short8*)(BF + ((size_t)(kb * ctgTot + cg + ct) * 64 + lane) * 8);
      acc[ct] = __builtin_amdgcn_mfma_f32_16x16x32_bf16(a, b, acc[ct], 0, 0, 0);
    }
  }

  const int orow = row0 + ((lane >> 4) << 2);
#pragma unroll
  for (int ct = 0; ct < CT; ++ct) {
    int col = (cg + ct) * 16 + (lane & 15);
#pragma unroll
    for (int rg = 0; rg < 4; ++rg) {
      int rr = orow + rg;
      if (rr >= nrows) continue;
      float v = acc[ct][rg];
      if (RELU) v = fmaxf(v, 0.f);
      if (OUTBF) Cb[(size_t)rr * ldc + col] = f2b(v);
      else       Cf[(size_t)rr * ldc + col] = v;
    }
  }
}

// ============ fused LSTM cell: gates GEMM (K up to 256) + pointwise ============
__global__ __launch_bounds__(256)
void lstm_cell(const float* __restrict__ Ax, int ldx,
               const float* __restrict__ Ah, int ldh_in,
               const unsigned short* __restrict__ BF,
               const float* __restrict__ bi, const float* __restrict__ bh,
               const float* __restrict__ cin, float* __restrict__ cout,
               float* __restrict__ hout, int ldh_out,
               float* __restrict__ hlast, int kbmax, int nrows)
{
  __shared__ unsigned short lb[2][16384];  // 2 x 32KB
  const int tid = threadIdx.x, lane = tid & 63, wid = tid >> 6;
  const int row0 = blockIdx.x * 64 + wid * 16;
  const int r = row0 + (lane & 15);
  const bool rok = r < nrows;
  const int koff = (lane >> 4) << 3;

  f32x4 acc[32];
#pragma unroll
  for (int ct = 0; ct < 32; ++ct) {
    int col = ct * 16 + (lane & 15);
    float b = bi[col] + bh[col];
    acc[ct] = (f32x4){b, b, b, b};
  }

  // stage kb=0
#pragma unroll
  for (int j = 0; j < 8; ++j) {
    int chunk = wid * 8 + j;
    const unsigned short* g = BF + chunk * 512 + lane * 8;
    __builtin_amdgcn_global_load_lds((const __attribute__((address_space(1))) void*)g,
                                     (__attribute__((address_space(3))) void*)(&lb[0][chunk * 512]),
                                     16, 0, 0);
  }

  for (int kb = 0; kb < kbmax; ++kb) {
    __syncthreads();  // drains vmcnt: lb[kb&1] ready; previous buffer free
    if (kb + 1 < kbmax) {
#pragma unroll
      for (int j = 0; j < 8; ++j) {
        int chunk = wid * 8 + j;
        const unsigned short* g = BF + (size_t)(kb + 1) * 16384 + chunk * 512 + lane * 8;
        __builtin_amdgcn_global_load_lds((const __attribute__((address_space(1))) void*)g,
                                         (__attribute__((address_space(3))) void*)(&lb[(kb + 1) & 1][chunk * 512]),
                                         16, 0, 0);
      }
    }
    short8 a = {};
    if (rok) {
      const float* p = (kb < 4) ? (Ax + (size_t)r * ldx + kb * 32 + koff)
                                : (Ah + (size_t)r * ldh_in + (kb - 4) * 32 + koff);
      a = cvt_frag(ld4(p), ld4(p + 4));
    }
    const unsigned short* lbp = lb[kb & 1];
#pragma unroll
    for (int ct = 0; ct < 32; ++ct) {
      const short8 b = *(const short8*)(lbp + (ct * 64 + lane) * 8);
      acc[ct] = __builtin_amdgcn_mfma_f32_16x16x32_bf16(a, b, acc[ct], 0, 0, 0);
    }
  }

  const int orow = row0 + ((lane >> 4) << 2);
#pragma unroll
  for (int ct = 0; ct < 8; ++ct) {
    int col = ct * 16 + (lane & 15);
#pragma unroll
    for (int rg = 0; rg < 4; ++rg) {
      int rr = orow + rg;
      if (rr >= nrows) continue;
      float gi = acc[ct][rg], gf = acc[ct + 8][rg], gg = acc[ct + 16][rg], go = acc[ct + 24][rg];
      float si = 1.f / (1.f + __expf(-gi));
      float sf = 1.f / (1.f + __expf(-gf));
      float so = 1.f / (1.f + __expf(-go));
      float cp = cin ? cin[(size_t)rr * 128 + col] : 0.f;
      float cc = sf * cp + si * tanhf(gg);
      float hh = so * tanhf(cc);
      cout[(size_t)rr * 128 + col] = cc;
      hout[(size_t)rr * ldh_out + col] = hh;
      if (hlast) hlast[(size_t)rr * 128 + col] = hh;
    }
  }
}

// ============ encoder tail ============
__global__ void encoder_finish_kernel(float* __restrict__ h0, const float* __restrict__ itype,
                                      const float* __restrict__ mask, const float* __restrict__ Wenc,
                                      const float* __restrict__ benc, int n)
{
  int idx = blockIdx.x * blockDim.x + threadIdx.x;
  if (idx >= n * 128) return;
  int nn = idx >> 7, j = idx & 127;
  float v = h0[idx]
          + itype[nn * 3 + 0] * Wenc[128 * 128 + j]
          + itype[nn * 3 + 1] * Wenc[129 * 128 + j]
          + itype[nn * 3 + 2] * Wenc[130 * 128 + j]
          + benc[j];
  h0[idx] = fmaxf(v, 0.f) * mask[nn];
}

// ============ CSR build ============
__global__ void count_kernel(const int* __restrict__ dst, int* __restrict__ cnt, int E, int EP)
{
  int e = blockIdx.x * blockDim.x + threadIdx.x;
  if (e >= EP) return;
  int d = (e < E) ? dst[e] : (e - E);
  atomicAdd(&cnt[d], 1);
}

__global__ void scan_kernel(const int* __restrict__ cnt, int* __restrict__ indptr, int n)
{
  __shared__ int wsum[16];
  int tid = threadIdx.x;
  int lane = tid & 63, wv = tid >> 6;
  int run = 0;
  for (int base = 0; base < n; base += 1024) {
    int idx = base + tid;
    int v = (idx < n) ? cnt[idx] : 0;
    int x = v;
#pragma unroll
    for (int off = 1; off < 64; off <<= 1) { int y = __shfl_up(x, off); if (lane >= off) x += y; }
    if (lane == 63) wsum[wv] = x;
    __syncthreads();
    if (wv == 0) {
      int t = (lane < 16) ? wsum[lane] : 0;
#pragma unroll
      for (int off = 1; off < 16; off <<= 1) { int y = __shfl_up(t, off); if (lane >= off) t += y; }
      if (lane < 16) wsum[lane] = t;
    }
    __syncthreads();
    int offs = wv ? wsum[wv - 1] : 0;
    int tot = wsum[15];
    if (idx < n) indptr[idx] = run + offs + x - v;
    run += tot;
    __syncthreads();
  }
  if (tid == 0) indptr[n] = run;
}

__global__ void fill_kernel(const int* __restrict__ src, const int* __restrict__ dst,
                            const int* __restrict__ indptr, int* __restrict__ fillc,
                            int* __restrict__ srcl, int E, int EP)
{
  int e = blockIdx.x * blockDim.x + threadIdx.x;
  if (e >= EP) return;
  int d, s;
  if (e < E) { d = dst[e]; s = src[e]; } else { d = e - E; s = e - E; }
  int pos = atomicAdd(&fillc[d], 1);
  srcl[indptr[d] + pos] = s;
}

// ============ GAT: per-node attention logits (bf16 xh) ============
__global__ void gat_att_kernel(const unsigned short* __restrict__ xhb,
                               const float* __restrict__ attS, const float* __restrict__ attD,
                               float* __restrict__ aS, float* __restrict__ aD, int n)
{
  int idx = blockIdx.x * blockDim.x + threadIdx.x;
  if (idx >= n * 4) return;
  int nn = idx >> 2, hd = idx & 3;
  const uint4* xr = (const uint4*)(xhb + (size_t)nn * 128 + hd * 32);
  const float* as_ = attS + hd * 32;
  const float* ad_ = attD + hd * 32;
  float s = 0.f, d = 0.f;
#pragma unroll
  for (int w = 0; w < 4; ++w) {
    uint4 v = xr[w];
    unsigned int u[4] = {v.x, v.y, v.z, v.w};
#pragma unroll
    for (int c = 0; c < 4; ++c) {
      float lo = b2f((unsigned short)(u[c] & 0xffff));
      float hi = b2f((unsigned short)(u[c] >> 16));
      int o = w * 8 + c * 2;
      s = fmaf(lo, as_[o], s);     d = fmaf(lo, ad_[o], d);
      s = fmaf(hi, as_[o + 1], s); d = fmaf(hi, ad_[o + 1], d);
    }
  }
  aS[idx] = s; aD[idx] = d;
}

// ============ GAT: stats + alpha (wave per dst, lane-parallel over edges) ============
__global__ __launch_bounds__(256)
void gat_stats_kernel(const float* __restrict__ aS, const float* __restrict__ aD,
                      const int* __restrict__ indptr, const int* __restrict__ srcl,
                      float* __restrict__ alpha4, int n)
{
  int wid = (int)((blockIdx.x * (size_t)blockDim.x + threadIdx.x) >> 6);
  int lane = threadIdx.x & 63;
  if (wid >= n) return;
  int eb = indptr[wid], ee = indptr[wid + 1];
  float4 ad = ld4(aD + wid * 4);
  float m0 = -3e38f, m1 = -3e38f, m2 = -3e38f, m3 = -3e38f;
  for (int i = eb + lane; i < ee; i += 64) {
    int s = srcl[i];
    float4 as = ld4(aS + s * 4);
    float e0 = as.x + ad.x; e0 = e0 > 0.f ? e0 : 0.2f * e0; m0 = fmaxf(m0, e0);
    float e1 = as.y + ad.y; e1 = e1 > 0.f ? e1 : 0.2f * e1; m1 = fmaxf(m1, e1);
    float e2 = as.z + ad.z; e2 = e2 > 0.f ? e2 : 0.2f * e2; m2 = fmaxf(m2, e2);
    float e3 = as.w + ad.w; e3 = e3 > 0.f ? e3 : 0.2f * e3; m3 = fmaxf(m3, e3);
  }
#pragma unroll
  for (int off = 32; off; off >>= 1) {
    m0 = fmaxf(m0, __shfl_xor(m0, off)); m1 = fmaxf(m1, __shfl_xor(m1, off));
    m2 = fmaxf(m2, __shfl_xor(m2, off)); m3 = fmaxf(m3, __shfl_xor(m3, off));
  }
  float s0 = 0.f, s1 = 0.f, s2 = 0.f, s3 = 0.f;
  for (int i = eb + lane; i < ee; i += 64) {
    int s = srcl[i];
    float4 as = ld4(aS + s * 4);
    float e0 = as.x + ad.x; e0 = e0 > 0.f ? e0 : 0.2f * e0; s0 += __expf(e0 - m0);
    float e1 = as.y + ad.y; e1 = e1 > 0.f ? e1 : 0.2f * e1; s1 += __expf(e1 - m1);
    float e2 = as.z + ad.z; e2 = e2 > 0.f ? e2 : 0.2f * e2; s2 += __expf(e2 - m2);
    float e3 = as.w + ad.w; e3 = e3 > 0.f ? e3 : 0.2f * e3; s3 += __expf(e3 - m3);
  }
#pragma unroll
  for (int off = 32; off; off >>= 1) {
    s0 += __shfl_xor(s0, off); s1 += __shfl_xor(s1, off);
    s2 += __shfl_xor(s2, off); s3 += __shfl_xor(s3, off);
  }
  float i0 = 1.f / (s0 + 1e-16f), i1 = 1.f / (s1 + 1e-16f);
  float i2 = 1.f / (s2 + 1e-16f), i3 = 1.f / (s3 + 1e-16f);
  for (int i = eb + lane; i < ee; i += 64) {
    int s = srcl[i];
    float4 as = ld4(aS + s * 4);
    float e0 = as.x + ad.x; e0 = e0 > 0.f ? e0 : 0.2f * e0;
    float e1 = as.y + ad.y; e1 = e1 > 0.f ? e1 : 0.2f * e1;
    float e2 = as.z + ad.z; e2 = e2 > 0.f ? e2 : 0.2f * e2;
    float e3 = as.w + ad.w; e3 = e3 > 0.f ? e3 : 0.2f * e3;
    float4 al = make_float4(__expf(e0 - m0) * i0, __expf(e1 - m1) * i1,
                            __expf(e2 - m2) * i2, __expf(e3 - m3) * i3);
    st4(alpha4 + (size_t)i * 4, al);
  }
}

// ============ GAT: slim weighted gather (wave per dst) ============
__global__ __launch_bounds__(256)
void gat_agg2_kernel(const unsigned short* __restrict__ xhb, const float* __restrict__ alpha4,
                     const int* __restrict__ indptr, const int* __restrict__ srcl,
                     const float* __restrict__ bgat, float* __restrict__ out, int ldo, int n)
{
  int wid = (int)((blockIdx.x * (size_t)blockDim.x + threadIdx.x) >> 6);
  int lane = threadIdx.x & 63;
  if (wid >= n) return;
  int eb = indptr[wid], ee = indptr[wid + 1];
  int hsel = lane >> 4;
  float acc0 = 0.f, acc1 = 0.f;
  for (int i = eb; i < ee; ++i) {
    int s = srcl[i];
    float4 a4 = ld4(alpha4 + (size_t)i * 4);
    float av = (hsel == 0) ? a4.x : (hsel == 1) ? a4.y : (hsel == 2) ? a4.z : a4.w;
    unsigned int px = *(const unsigned int*)(xhb + (size_t)s * 128 + lane * 2);
    acc0 = fmaf(av, b2f((unsigned short)(px & 0xffff)), acc0);
    acc1 = fmaf(av, b2f((unsigned short)(px >> 16)), acc1);
  }
  float2 o;
  o.x = acc0 + bgat[lane * 2];
  o.y = acc1 + bgat[lane * 2 + 1];
  *reinterpret_cast<float2*>(out + (size_t)wid * ldo + lane * 2) = o;
}

// ============ impact head layer 2 + |.| mean ============
__global__ __launch_bounds__(256)
void impact_out_kernel(const float* __restrict__ hid, const float* __restrict__ W2,
                       const float* __restrict__ b2, float* __restrict__ outp,
                       float* __restrict__ total, float wk, int n)
{
  __shared__ float red[256];
  int idx = blockIdx.x * 256 + threadIdx.x;
  float part = 0.f;
  if (idx < n) {
    const float* h = hid + (size_t)idx * 64;
    float o0 = b2[0], o1 = b2[1], o2 = b2[2];
#pragma unroll 8
    for (int k = 0; k < 64; ++k) {
      float v = h[k];
      o0 = fmaf(v, W2[k * 3 + 0], o0);
      o1 = fmaf(v, W2[k * 3 + 1], o1);
      o2 = fmaf(v, W2[k * 3 + 2], o2);
    }
    outp[(size_t)idx * 3 + 0] = o0;
    outp[(size_t)idx * 3 + 1] = o1;
    outp[(size_t)idx * 3 + 2] = o2;
    part = fabsf(o0) + fabsf(o1) + fabsf(o2);
  }
  red[threadIdx.x] = part;
  __syncthreads();
  for (int s = 128; s; s >>= 1) {
    if (threadIdx.x < s) red[threadIdx.x] += red[threadIdx.x + s];
    __syncthreads();
  }
  if (threadIdx.x == 0) atomicAdd(total, red[0] * wk);
}

// ============ host ============
extern "C" void kernel_launch(void* const* d_in, const int* in_sizes, int n_in,
                              void* d_out, int out_size, void* d_ws, size_t ws_size,
                              hipStream_t stream)
{
  const float* x     = (const float*)d_in[0];
  const int*   ei    = (const int*)  d_in[1];
  const float* mask  = (const float*)d_in[2];
  const float* itype = (const float*)d_in[3];
  const float* Wenc  = (const float*)d_in[4];
  const float* benc  = (const float*)d_in[5];
  const float* Wgat  = (const float*)d_in[6];
  const float* attS  = (const float*)d_in[7];
  const float* attD  = (const float*)d_in[8];
  const float* bgat  = (const float*)d_in[9];
  const float* W1    = (const float*)d_in[10];
  const float* b1    = (const float*)d_in[11];
  const float* W2    = (const float*)d_in[12];
  const float* b2    = (const float*)d_in[13];
  const float* Wih0  = (const float*)d_in[14];
  const float* Whh0  = (const float*)d_in[15];
  const float* bih0  = (const float*)d_in[16];
  const float* bhh0  = (const float*)d_in[17];
  const float* Wih1  = (const float*)d_in[18];
  const float* Whh1  = (const float*)d_in[19];
  const float* bih1  = (const float*)d_in[20];
  const float* bhh1  = (const float*)d_in[21];

  const int N  = in_sizes[0] / 128;
  const int E  = in_sizes[1] / 2;
  const int EP = E + N;

  float* out      = (float*)d_out;
  float* impacts  = out;
  float* temporal = out + (size_t)3 * N * 3;     // [N][3][128], ld 384
  float* hlast    = temporal + (size_t)N * 384;  // [N][128]
  float* total    = hlast + (size_t)N * 128;

  // ---- workspace layout (floats) ----
  float* ws = (float*)d_ws;
  float* regA = ws;                                   // EP*4 floats (alpha4 / impact hidden)
  float* hA   = regA + (size_t)EP * 4;                // N*128 (h0 during GAT phase)
  float* cA   = hA + (size_t)N * 128;                 // N*128
  float* cB   = cA + (size_t)N * 128;                 // N*128
  unsigned short* xhb = (unsigned short*)(cB + (size_t)N * 128);  // N*128 ushort
  float* aS   = cB + (size_t)N * 128 + (size_t)N * 64;
  float* aD   = aS + (size_t)N * 4;
  int* indptr = (int*)(aD + (size_t)N * 4);
  int* fillc  = indptr + (N + 1);
  int* srcl   = fillc + N;
  size_t ip = (size_t)((srcl + EP) - (int*)ws);
  ip = (ip + 7) & ~(size_t)7;                         // 32B align for frags
  unsigned short* frags = (unsigned short*)((int*)ws + ip);
  unsigned short* WencF = frags;                      // 16384
  unsigned short* WgatF = WencF + 16384;              // 3*16384
  unsigned short* W1F   = WgatF + 3 * 16384;          // 3*8192
  unsigned short* L0F   = W1F + 3 * 8192;             // 131072
  unsigned short* L1F   = L0F + 131072;               // 131072

  size_t need_fl = (size_t)EP * 4 + (size_t)N * 128 * 3 + (size_t)N * 64 + (size_t)N * 8
                 + ((size_t)2 * N + 1 + EP + 8) / 2 + 1 + (16384 * 4 + 8192 * 3 + 131072 * 2) / 2 + 16;
  if (ws_size < need_fl * 4) return;

  const int* esrc = ei;
  const int* edst = ei + E;
  const int rowTiles = (N + 63) / 64;

  // ---- build weight fragments ----
  build_frag_kmajor<<<64, 256, 0, stream>>>(Wenc, 128, WencF, 4, 8);
  for (int k = 0; k < 3; ++k) {
    build_frag_kmajor<<<64, 256, 0, stream>>>(Wgat + (size_t)k * 16384, 128, WgatF + (size_t)k * 16384, 4, 8);
    build_frag_kmajor<<<32, 256, 0, stream>>>(W1 + (size_t)k * 8192, 64, W1F + (size_t)k * 8192, 4, 4);
  }
  build_frag_lstm<<<512, 256, 0, stream>>>(Wih0, Whh0, L0F);
  build_frag_lstm<<<512, 256, 0, stream>>>(Wih1, Whh1, L1F);

  // ---- CSR by destination (self-loops appended) ----
  hipMemsetAsync(fillc, 0, (size_t)N * sizeof(int), stream);
  count_kernel<<<(EP + 255) / 256, 256, 0, stream>>>(edst, fillc, E, EP);
  scan_kernel<<<1, 1024, 0, stream>>>(fillc, indptr, N);
  hipMemsetAsync(fillc, 0, (size_t)N * sizeof(int), stream);
  fill_kernel<<<(EP + 255) / 256, 256, 0, stream>>>(esrc, edst, indptr, fillc, srcl, E, EP);

  // ---- encoder ----
  gemm_mfma<8, 4, 0, 0><<<dim3(rowTiles, 1), 256, 0, stream>>>(
      x, 128, WencF, 8, hA, nullptr, 128, nullptr, N);
  encoder_finish_kernel<<<(N * 128 + 255) / 256, 256, 0, stream>>>(hA, itype, mask, Wenc, benc, N);

  hipMemsetAsync(total, 0, sizeof(float), stream);

  const int waveGrid = (N * 64 + 255) / 256;

  // ---- 3 GAT hops + impact heads ----
  for (int k = 0; k < 3; ++k) {
    const float* hin = (k == 0) ? hA : (temporal + (size_t)(k - 1) * 128);
    int ldin = (k == 0) ? 128 : 384;
    gemm_mfma<8, 4, 1, 0><<<dim3(rowTiles, 1), 256, 0, stream>>>(
        hin, ldin, WgatF + (size_t)k * 16384, 8, nullptr, xhb, 128, nullptr, N);
    gat_att_kernel<<<(N * 4 + 255) / 256, 256, 0, stream>>>(xhb, attS + k * 128, attD + k * 128, aS, aD, N);
    gat_stats_kernel<<<waveGrid, 256, 0, stream>>>(aS, aD, indptr, srcl, regA, N);
    gat_agg2_kernel<<<waveGrid, 256, 0, stream>>>(xhb, regA, indptr, srcl, bgat + k * 128,
                                                  temporal + (size_t)k * 128, 384, N);
    gemm_mfma<4, 4, 0, 1><<<dim3(rowTiles, 1), 256, 0, stream>>>(
        temporal + (size_t)k * 128, 384, W1F + (size_t)k * 8192, 4,
        regA, nullptr, 64, b1 + k * 64, N);
    float wk = ((k == 0) ? 1.f : (k == 1) ? 0.5f : 0.25f) / (3.0f * (float)N);
    impact_out_kernel<<<(N + 255) / 256, 256, 0, stream>>>(regA, W2 + k * 192, b2 + k * 3,
                                                           impacts + (size_t)k * N * 3, total, wk, N);
  }

  // ---- fused 2-layer LSTM over T=3 ----
  for (int t = 0; t < 3; ++t) {
    // layer 0: x = temporal slice t, h = hA (t>0), c = cA
    lstm_cell<<<rowTiles, 256, 0, stream>>>(
        temporal + (size_t)t * 128, 384, hA, 128, L0F, bih0, bhh0,
        (t == 0 ? nullptr : cA), cA, hA, 128, nullptr, (t == 0 ? 4 : 8), N);
    // layer 1: x = hA, h = temporal slice t-1, c = cB; writes temporal slice t
    lstm_cell<<<rowTiles, 256, 0, stream>>>(
        hA, 128, temporal + (size_t)(t - 1) * 128, 384, L1F, bih1, bhh1,
        (t == 0 ? nullptr : cB), cB, temporal + (size_t)t * 128, 384,
        (t == 2 ? hlast : nullptr), (t == 0 ? 4 : 8), N);
  }
}